// Round 7
// baseline (268.626 us; speedup 1.0000x reference)
//
#include <hip/hip_runtime.h>
#include <math.h>

#define IMG_W 512
#define IMG_H 512
#define NB 32
#define NC 3
#define PLANE (IMG_H * IMG_W)      // 262144 px per channel

#define TILE_W 32
#define TILE_H 32
#define TILES_X (IMG_W / TILE_W)   // 16
#define TILES_PER_B 256
#define NBLOCKS (NB * TILES_PER_B) // 8192

#define LDSF 6144                  // 24 KB staging tile (floats)

typedef float vfloat4 __attribute__((ext_vector_type(4)));

// ws layout: ws[lin] = num, ws[NBLOCKS + lin] = den.  lin = tile*32 + b.

__global__ __launch_bounds__(256) void recon_main(
    const float* __restrict__ theta,
    const float* __restrict__ img_R,
    const float* __restrict__ img_orig,
    float* __restrict__ ws)
{
    __shared__ __align__(16) float tileLds[LDSF];
    __shared__ float snum[4];
    __shared__ float sden[4];

    const int lin  = blockIdx.x;       // 0..8191
    const int b    = lin & (NB - 1);   // batch-interleave: load balance across CUs/XCDs
    const int tile = lin >> 5;         // 0..255
    const int tx = (tile & (TILES_X - 1)) * TILE_W;
    const int ty = (tile >> 4) * TILE_H;

    const int tid  = threadIdx.x;
    const int trow = tid >> 3;         // 0..31
    const int tcol = (tid & 7) * 4;    // 0..28

    // --- per-batch affine (uniform across block) ---
    const float ang   = theta[b * 3 + 0];
    const float s     = theta[b * 3 + 1];
    const float shift = 100.0f * theta[b * 3 + 2];
    float sn, cs;
    sincosf(ang, &sn, &cs);
    const float alpha = s * cs;
    const float beta  = s * sn;
    const float tx_a = (1.0f - alpha) * 256.0f - beta * 256.0f + shift;
    const float ty_a = beta * 256.0f + (1.0f - alpha) * 256.0f;
    const float Cc = alpha + beta + 2.0f * tx_a / 511.0f - 1.0f;
    const float Fc = -beta + alpha + 2.0f * ty_a / 511.0f - 1.0f;
    // source coords: x = X0 + alpha*w + beta*h ; y = Y0 - beta*w + alpha*h
    const float X0 = 255.5f * (Cc + 1.0f - alpha - beta);
    const float Y0 = 255.5f * (Fc + 1.0f + beta - alpha);

    // --- block-uniform source bbox (affine extrema at tile corners) ---
    const float fx_lo = (float)tx, fx_hi = (float)(tx + TILE_W - 1);
    const float fy_lo = (float)ty, fy_hi = (float)(ty + TILE_H - 1);
    const float cxA = X0 + alpha * fx_lo + beta * fy_lo;
    const float cxB = X0 + alpha * fx_hi + beta * fy_lo;
    const float cxC = X0 + alpha * fx_lo + beta * fy_hi;
    const float cxD = X0 + alpha * fx_hi + beta * fy_hi;
    const float cyA = Y0 - beta * fx_lo + alpha * fy_lo;
    const float cyB = Y0 - beta * fx_hi + alpha * fy_lo;
    const float cyC = Y0 - beta * fx_lo + alpha * fy_hi;
    const float cyD = Y0 - beta * fx_hi + alpha * fy_hi;
    const float min_x = fminf(fminf(cxA, cxB), fminf(cxC, cxD));
    const float max_x = fmaxf(fmaxf(cxA, cxB), fmaxf(cxC, cxD));
    const float min_y = fminf(fminf(cyA, cyB), fminf(cyC, cyD));
    const float max_y = fmaxf(fmaxf(cyA, cyB), fmaxf(cyC, cyD));

    // --- Tier 0: tile maps fully outside the source image -> zero contribution ---
    if (max_x < -1.01f || min_x > 512.01f || max_y < -1.01f || min_y > 512.01f) {
        if (tid == 0) { ws[lin] = 0.0f; ws[NBLOCKS + lin] = 0.0f; }
        return;
    }

    // interior: no clamps / no validity needed (0.5px jitter margin)
    const bool interior = (min_x > 0.5f) && (max_x < 510.0f) &&
                          (min_y > 0.5f) && (max_y < 510.0f);

    // padded bbox (+1 px guard against corner-vs-pixel rounding)
    int xlo = (int)floorf(min_x) - 1;
    int xhi = (int)floorf(max_x) + 2;
    xlo = min(max(xlo, 0), 511);
    xhi = min(max(xhi, 0), 511);
    xlo &= ~3;                          // 16B-align staging rows
    int ylo = (int)floorf(min_y) - 1;
    int yhi = (int)floorf(max_y) + 2;
    ylo = min(max(ylo, 0), 511);
    yhi = min(max(yhi, 0), 511);

    const int bw = xhi - xlo + 1;
    const int bh = yhi - ylo + 1;
    int stride = (bw + 3) & ~3;
    if (((stride >> 2) & 1) == 0) stride += 4;   // stride/4 odd: bank decorrelation
    const int nq4 = stride >> 2;
    const int sb = stride * bh;
    const bool okw   = (nq4 <= 32);
    const bool tier1 = okw && (3 * sb <= LDSF);  // all 3 channels staged, 1 barrier
    const bool tier2 = okw && !tier1 && (sb <= LDSF);

    const float* orig_b = img_orig + (size_t)b * NC * PLANE;
    const float* R_b    = img_R    + (size_t)b * NC * PLANE;

    const int h  = ty + trow;
    const int w0 = tx + tcol;
    const int p0 = h * IMG_W + w0;

    const float xb = X0 + alpha * (float)w0 + beta * (float)h;
    const float yb = Y0 - beta * (float)w0 + alpha * (float)h;

    int   xcA[4], yi0a[4], yi1a[4], sl0[4], sl1[4];
    float w00[4], w10[4], w01[4], w11[4], mk[4];
    float den_acc = 0.0f;

    if (interior) {
#pragma unroll
        for (int j = 0; j < 4; ++j) {
            const float x = xb + alpha * (float)j;
            const float y = yb - beta  * (float)j;
            const float x0f = floorf(x), y0f = floorf(y);
            const float fx1 = x - x0f,  fy1 = y - y0f;
            const float fx0 = 1.0f - fx1, fy0 = 1.0f - fy1;
            const int xi0 = (int)x0f, yi0 = (int)y0f;
            xcA[j] = xi0; yi0a[j] = yi0; yi1a[j] = yi0 + 1;
            sl0[j] = 0;   sl1[j] = 1;
            w00[j] = fx0 * fy0; w10[j] = fx1 * fy0;
            w01[j] = fx0 * fy1; w11[j] = fx1 * fy1;
            mk[j]  = 1.0f;
            den_acc += 1.0f;
        }
    } else {
#pragma unroll
        for (int j = 0; j < 4; ++j) {
            const float x = xb + alpha * (float)j;
            const float y = yb - beta  * (float)j;
            const float x0f = floorf(x), y0f = floorf(y);
            const float fx1 = x - x0f,  fy1 = y - y0f;
            const float fx0 = 1.0f - fx1, fy0 = 1.0f - fy1;
            const float vx0 = (x0f >=  0.0f && x0f <= 511.0f) ? 1.0f : 0.0f;
            const float vx1 = (x0f >= -1.0f && x0f <= 510.0f) ? 1.0f : 0.0f;
            const float vy0 = (y0f >=  0.0f && y0f <= 511.0f) ? 1.0f : 0.0f;
            const float vy1 = (y0f >= -1.0f && y0f <= 510.0f) ? 1.0f : 0.0f;
            const int xi0 = (int)fminf(fmaxf(x0f,        0.0f), 511.0f);
            const int xi1 = (int)fminf(fmaxf(x0f + 1.0f, 0.0f), 511.0f);
            yi0a[j] = (int)fminf(fmaxf(y0f,        0.0f), 511.0f);
            yi1a[j] = (int)fminf(fmaxf(y0f + 1.0f, 0.0f), 511.0f);
            const int xc = min(xi0, 510);
            xcA[j] = xc; sl0[j] = xi0 - xc; sl1[j] = xi1 - xc;
            w00[j] = fx0 * fy0 * vx0 * vy0;
            w10[j] = fx1 * fy0 * vx1 * vy0;
            w01[j] = fx0 * fy1 * vx0 * vy1;
            w11[j] = fx1 * fy1 * vx1 * vy1;
            mk[j]  = w00[j] + w10[j] + w01[j] + w11[j];
            den_acc += mk[j];
        }
    }

    float nrm[4] = {0.0f, 0.0f, 0.0f, 0.0f};

    if (tier1) {
        int l0[4], l1[4];
#pragma unroll
        for (int j = 0; j < 4; ++j) {
            l0[j] = (yi0a[j] - ylo) * stride + (xcA[j] - xlo);
            l1[j] = (yi1a[j] - ylo) * stride + (xcA[j] - xlo);
        }
        const int qq  = tid & 31;
        const int r00 = tid >> 5;
        const int col = xlo + (qq << 2);
        if (col <= xhi) {
            for (int c = 0; c < NC; ++c) {
                const float* plane = orig_b + c * PLANE;
                float* dst = tileLds + c * sb;
                for (int r = r00; r < bh; r += 8)
                    *(vfloat4*)(dst + r * stride + (qq << 2)) =
                        *(const vfloat4*)(plane + (ylo + r) * IMG_W + col);
            }
        }
        __syncthreads();
#pragma unroll
        for (int c = 0; c < NC; ++c) {
            const float* lsrc = tileLds + c * sb;
            const vfloat4 rv = __builtin_nontemporal_load(
                                 (const vfloat4*)(R_b + c * PLANE + p0));
            const float rj[4] = {rv.x, rv.y, rv.z, rv.w};
#pragma unroll
            for (int j = 0; j < 4; ++j) {
                const float u0 = lsrc[l0[j]], u1 = lsrc[l0[j] + 1];
                const float v0 = lsrc[l1[j]], v1 = lsrc[l1[j] + 1];
                const float s00 = sl0[j] ? u1 : u0;
                const float s10 = sl1[j] ? u1 : u0;
                const float s01 = sl0[j] ? v1 : v0;
                const float s11 = sl1[j] ? v1 : v0;
                const float warped = s00 * w00[j] + s10 * w10[j]
                                   + s01 * w01[j] + s11 * w11[j];
                nrm[j] += fabsf(rj[j] - warped);
            }
        }
    } else if (tier2) {
        int l0[4], l1[4];
#pragma unroll
        for (int j = 0; j < 4; ++j) {
            l0[j] = (yi0a[j] - ylo) * stride + (xcA[j] - xlo);
            l1[j] = (yi1a[j] - ylo) * stride + (xcA[j] - xlo);
        }
        const int qq  = tid & 31;
        const int r00 = tid >> 5;
        const int col = xlo + (qq << 2);
        const bool doload = (col <= xhi);
        for (int c = 0; c < NC; ++c) {
            if (c) __syncthreads();
            const float* plane = orig_b + c * PLANE;
            if (doload) {
                for (int r = r00; r < bh; r += 8)
                    *(vfloat4*)(&tileLds[r * stride + (qq << 2)]) =
                        *(const vfloat4*)(plane + (ylo + r) * IMG_W + col);
            }
            __syncthreads();
            const vfloat4 rv = __builtin_nontemporal_load(
                                 (const vfloat4*)(R_b + c * PLANE + p0));
            const float rj[4] = {rv.x, rv.y, rv.z, rv.w};
#pragma unroll
            for (int j = 0; j < 4; ++j) {
                const float u0 = tileLds[l0[j]], u1 = tileLds[l0[j] + 1];
                const float v0 = tileLds[l1[j]], v1 = tileLds[l1[j] + 1];
                const float s00 = sl0[j] ? u1 : u0;
                const float s10 = sl1[j] ? u1 : u0;
                const float s01 = sl0[j] ? v1 : v0;
                const float s11 = sl1[j] ? v1 : v0;
                const float warped = s00 * w00[j] + s10 * w10[j]
                                   + s01 * w01[j] + s11 * w11[j];
                nrm[j] += fabsf(rj[j] - warped);
            }
        }
    } else {
        // direct-gather fallback (big minification: little reuse anyway)
        int a0[4], a1[4];
#pragma unroll
        for (int j = 0; j < 4; ++j) {
            a0[j] = yi0a[j] * IMG_W + xcA[j];
            a1[j] = yi1a[j] * IMG_W + xcA[j];
        }
#pragma unroll
        for (int c = 0; c < NC; ++c) {
            const float* plane = orig_b + c * PLANE;
            const vfloat4 rv = __builtin_nontemporal_load(
                                 (const vfloat4*)(R_b + c * PLANE + p0));
            const float rj[4] = {rv.x, rv.y, rv.z, rv.w};
#pragma unroll
            for (int j = 0; j < 4; ++j) {
                const float2 t0 = *(const float2*)(plane + a0[j]);
                const float2 t1 = *(const float2*)(plane + a1[j]);
                const float s00 = sl0[j] ? t0.y : t0.x;
                const float s10 = sl1[j] ? t0.y : t0.x;
                const float s01 = sl0[j] ? t1.y : t1.x;
                const float s11 = sl1[j] ? t1.y : t1.x;
                const float warped = s00 * w00[j] + s10 * w10[j]
                                   + s01 * w01[j] + s11 * w11[j];
                nrm[j] += fabsf(rj[j] - warped);
            }
        }
    }

    float num_acc = 0.0f;
#pragma unroll
    for (int j = 0; j < 4; ++j) num_acc += mk[j] * nrm[j];

    // --- wave (64) reduction ---
#pragma unroll
    for (int off = 32; off > 0; off >>= 1) {
        num_acc += __shfl_down(num_acc, off);
        den_acc += __shfl_down(den_acc, off);
    }

    const int wave = tid >> 6;
    const int lane = tid & 63;
    if (lane == 0) { snum[wave] = num_acc; sden[wave] = den_acc; }
    __syncthreads();
    if (tid == 0) {
        ws[lin]           = snum[0] + snum[1] + snum[2] + snum[3];
        ws[NBLOCKS + lin] = sden[0] + sden[1] + sden[2] + sden[3];
    }
}

__global__ __launch_bounds__(256) void recon_final(
    const float* __restrict__ ws,
    float* __restrict__ out)
{
    __shared__ float sloss[NB];
    const int t = threadIdx.x;
    const int b = t >> 3;              // 0..31 (8 threads per batch)
    const int j = t & 7;               // 0..7

    float n = 0.0f, d = 0.0f;
    for (int k = 0; k < 32; ++k) {
        const int tile = j * 32 + k;
        const int lin  = tile * NB + b;
        n += ws[lin];
        d += ws[NBLOCKS + lin];
    }
#pragma unroll
    for (int off = 4; off > 0; off >>= 1) {
        n += __shfl_down(n, off);
        d += __shfl_down(d, off);
    }
    if (j == 0) sloss[b] = 10.0f * (n + 1e-16f) / (d + 1e-16f);
    __syncthreads();
    if (t == 0) {
        float L = 0.0f;
#pragma unroll
        for (int i = 0; i < NB; ++i) L += sloss[i];
        out[0] = L * (1.0f / (float)NB);
    }
}

extern "C" void kernel_launch(void* const* d_in, const int* in_sizes, int n_in,
                              void* d_out, int out_size, void* d_ws, size_t ws_size,
                              hipStream_t stream) {
    const float* theta    = (const float*)d_in[0];
    const float* img_R    = (const float*)d_in[1];
    const float* img_orig = (const float*)d_in[2];
    float* out = (float*)d_out;
    float* ws  = (float*)d_ws;

    recon_main<<<NBLOCKS, 256, 0, stream>>>(theta, img_R, img_orig, ws);
    recon_final<<<1, 256, 0, stream>>>(ws, out);
}